// Round 7
// baseline (304.912 us; speedup 1.0000x reference)
//
#include <hip/hip_runtime.h>
#include <hip/hip_bf16.h>
#include <math.h>

#define D_MODEL 1024
#define NH      16
#define DK      64
#define S_LEN   2048
#define BATCH   2
#define M_ROWS  4096

typedef _Float16 f16;
typedef _Float16 f16x8 __attribute__((ext_vector_type(8)));
typedef float    f32x4 __attribute__((ext_vector_type(4)));

// native 2^x (v_exp_f32)
__device__ __forceinline__ float exp2_fast(float x) {
    float r;
    asm("v_exp_f32 %0, %1" : "=v"(r) : "v"(x));
    return r;
}

// V key permutation within a 64-block: key' = [b5][b3 b2][b4][b1 b0]
// so PV A-fragment key order pi(g,j) matches contiguous V reads.
__device__ __forceinline__ int perm6(int k) {
    return (k & 35) | ((k & 12) << 1) | ((k & 16) >> 2);
}

// ---------------------------------------------------------------------------
// fp32 -> fp16 conversion, 8 elems/thread, up to 4 tensors via blockIdx.y
// ---------------------------------------------------------------------------
__global__ __launch_bounds__(256) void cvt_f32_to_f16(
    const float* __restrict__ a, const float* __restrict__ b,
    const float* __restrict__ c, const float* __restrict__ d,
    f16* __restrict__ oa, f16* __restrict__ ob,
    f16* __restrict__ oc, f16* __restrict__ od, int n8) {
    const int y = blockIdx.y;
    const float* s = (y == 0) ? a : (y == 1) ? b : (y == 2) ? c : d;
    f16* o        = (y == 0) ? oa : (y == 1) ? ob : (y == 2) ? oc : od;
    if (s == nullptr) return;
    const int i = blockIdx.x * 256 + threadIdx.x;
    if (i >= n8) return;
    const size_t e = (size_t)i * 8;
    const float4 v0 = *(const float4*)&s[e];
    const float4 v1 = *(const float4*)&s[e + 4];
    f16x8 r = {(f16)v0.x, (f16)v0.y, (f16)v0.z, (f16)v0.w,
               (f16)v1.x, (f16)v1.y, (f16)v1.z, (f16)v1.w};
    *(f16x8*)&o[e] = r;
}

// ---------------------------------------------------------------------------
// async global->LDS staging, 16B per lane (HW: wave-uniform base + lane*16)
// ---------------------------------------------------------------------------
__device__ __forceinline__ void stage16(const f16* g, f16* l) {
    __builtin_amdgcn_global_load_lds(
        (const __attribute__((address_space(1))) unsigned int*)g,
        (__attribute__((address_space(3))) unsigned int*)l, 16, 0, 0);
}

// ---------------------------------------------------------------------------
// 128x128 fp16 MFMA GEMM body (normal orientation).
// mode 0: f16 out head-split [b][h][s][dk]; mode 2: f32 out [m][n].
// ---------------------------------------------------------------------------
__device__ __forceinline__ void gemm_body(f16* As, f16* Bs,
                                          const f16* __restrict__ X, const f16* __restrict__ W,
                                          const float* __restrict__ bias, void* __restrict__ Yv,
                                          const int mode, const float oscale) {
    const int tid = threadIdx.x;
    const int lane = tid & 63;
    const int w  = tid >> 6;
    const int wm = w >> 1, wn = w & 1;
    const int l15 = lane & 15, lhi = lane >> 4;
    const int m0 = blockIdx.y * 128, n0 = blockIdx.x * 128;

    const int srow = tid >> 2;
    const int scol = (tid & 3) * 8;

    f32x4 acc[4][4] = {};

    for (int k0 = 0; k0 < D_MODEL; k0 += 32) {
        __syncthreads();
        stage16(&X[(size_t)(m0 + srow) * D_MODEL + k0 + scol],      &As[tid * 8]);
        stage16(&X[(size_t)(m0 + 64 + srow) * D_MODEL + k0 + scol], &As[2048 + tid * 8]);
        stage16(&W[(size_t)(n0 + srow) * D_MODEL + k0 + scol],      &Bs[tid * 8]);
        stage16(&W[(size_t)(n0 + 64 + srow) * D_MODEL + k0 + scol], &Bs[2048 + tid * 8]);
        __syncthreads();
        f16x8 af[4], bf[4];
#pragma unroll
        for (int mt = 0; mt < 4; ++mt) af[mt] = *(const f16x8*)&As[(wm * 64 + mt * 16 + l15) * 32 + lhi * 8];
#pragma unroll
        for (int nt = 0; nt < 4; ++nt) bf[nt] = *(const f16x8*)&Bs[(wn * 64 + nt * 16 + l15) * 32 + lhi * 8];
#pragma unroll
        for (int mt = 0; mt < 4; ++mt)
#pragma unroll
            for (int nt = 0; nt < 4; ++nt)
                acc[mt][nt] = __builtin_amdgcn_mfma_f32_16x16x32_f16(af[mt], bf[nt], acc[mt][nt], 0, 0, 0);
    }

#pragma unroll
    for (int mt = 0; mt < 4; ++mt)
#pragma unroll
        for (int nt = 0; nt < 4; ++nt) {
            const int n = n0 + wn * 64 + nt * 16 + l15;
            const float bn = bias[n];
#pragma unroll
            for (int r = 0; r < 4; ++r) {
                const int m = m0 + wm * 64 + mt * 16 + lhi * 4 + r;
                const float v = (acc[mt][nt][r] + bn) * oscale;
                if (mode == 0) {
                    ((f16*)Yv)[((((size_t)(m >> 11) * NH + (n >> 6)) * S_LEN) + (m & 2047)) * DK + (n & 63)] = (f16)v;
                } else {
                    ((float*)Yv)[(size_t)m * D_MODEL + n] = v;
                }
            }
        }
}

// ---------------------------------------------------------------------------
// 128x128 OPERAND-SWAPPED body for the V projection: A=W rows (n), B=X rows
// (m) -> D[row=n][col=m]. Lanes run along m=s -> coalesced-ish writes into
// the transposed, key-permuted layout vt[bh][dk][s'] (s' = perm6 in 64-blk).
// ---------------------------------------------------------------------------
__device__ __forceinline__ void gemm_body_vswap(f16* As, f16* Bs,
                                                const f16* __restrict__ X, const f16* __restrict__ W,
                                                const float* __restrict__ bias, f16* __restrict__ vt) {
    const int tid = threadIdx.x;
    const int lane = tid & 63;
    const int w  = tid >> 6;
    const int wm = w >> 1, wn = w & 1;
    const int l15 = lane & 15, lhi = lane >> 4;
    const int m0 = blockIdx.y * 128, n0 = blockIdx.x * 128;

    const int srow = tid >> 2;
    const int scol = (tid & 3) * 8;

    f32x4 acc[4][4] = {};

    for (int k0 = 0; k0 < D_MODEL; k0 += 32) {
        __syncthreads();
        stage16(&X[(size_t)(m0 + srow) * D_MODEL + k0 + scol],      &As[tid * 8]);
        stage16(&X[(size_t)(m0 + 64 + srow) * D_MODEL + k0 + scol], &As[2048 + tid * 8]);
        stage16(&W[(size_t)(n0 + srow) * D_MODEL + k0 + scol],      &Bs[tid * 8]);
        stage16(&W[(size_t)(n0 + 64 + srow) * D_MODEL + k0 + scol], &Bs[2048 + tid * 8]);
        __syncthreads();
        f16x8 af[4], bf[4];
#pragma unroll
        for (int at = 0; at < 4; ++at) af[at] = *(const f16x8*)&Bs[(wm * 64 + at * 16 + l15) * 32 + lhi * 8];
#pragma unroll
        for (int bt = 0; bt < 4; ++bt) bf[bt] = *(const f16x8*)&As[(wn * 64 + bt * 16 + l15) * 32 + lhi * 8];
#pragma unroll
        for (int at = 0; at < 4; ++at)
#pragma unroll
            for (int bt = 0; bt < 4; ++bt)
                acc[at][bt] = __builtin_amdgcn_mfma_f32_16x16x32_f16(af[at], bf[bt], acc[at][bt], 0, 0, 0);
    }

#pragma unroll
    for (int at = 0; at < 4; ++at)
#pragma unroll
        for (int bt = 0; bt < 4; ++bt) {
            const int m = m0 + wn * 64 + bt * 16 + l15;   // = b*2048 + s
            const int b = m >> 11, s = m & 2047;
#pragma unroll
            for (int r = 0; r < 4; ++r) {
                const int n = n0 + wm * 64 + at * 16 + lhi * 4 + r;  // = h*64 + d
                const float v = acc[at][bt][r] + bias[n];
                const int s2 = (s & ~63) | perm6(s & 63);
                vt[(((size_t)b * NH + (n >> 6)) * DK + (n & 63)) * S_LEN + s2] = (f16)v;
            }
        }
}

__global__ __launch_bounds__(256) void qkv_gemm(
    const f16* __restrict__ Xq, const f16* __restrict__ Xk, const f16* __restrict__ Xv,
    const f16* __restrict__ Wq, const f16* __restrict__ Wk, const f16* __restrict__ Wv,
    const float* __restrict__ bq, const float* __restrict__ bk, const float* __restrict__ bv,
    f16* __restrict__ qh, f16* __restrict__ kh, f16* __restrict__ vt) {
    __shared__ f16 As[128 * 32];
    __shared__ f16 Bs[128 * 32];
    const int z = blockIdx.z;
    if (z == 2) {
        gemm_body_vswap(As, Bs, Xv, Wv, bv, vt);
    } else if (z == 0) {
        // fold softmax scale 1/sqrt(64) AND log2(e) into Q projection
        gemm_body(As, Bs, Xq, Wq, bq, qh, 0, 0.125f * 1.44269504f);
    } else {
        gemm_body(As, Bs, Xk, Wk, bk, kh, 0, 1.0f);
    }
}

// ---------------------------------------------------------------------------
// Output GEMM, 64x128 tiles (grid 8x64 = 512 blocks = 2/CU), f32 out.
// ---------------------------------------------------------------------------
__global__ __launch_bounds__(256) void out_gemm(const f16* __restrict__ X, const f16* __restrict__ W,
                                                const float* __restrict__ bias, float* __restrict__ Y) {
    __shared__ f16 As[64 * 32];
    __shared__ f16 Bs[128 * 32];
    const int tid = threadIdx.x;
    const int lane = tid & 63;
    const int w  = tid >> 6;
    const int l15 = lane & 15, lhi = lane >> 4;
    const int m0 = blockIdx.y * 64, n0 = blockIdx.x * 128;

    const int srow = tid >> 2;
    const int scol = (tid & 3) * 8;

    f32x4 acc[4][2] = {};

    for (int k0 = 0; k0 < D_MODEL; k0 += 32) {
        __syncthreads();
        stage16(&X[(size_t)(m0 + srow) * D_MODEL + k0 + scol],      &As[tid * 8]);
        stage16(&W[(size_t)(n0 + srow) * D_MODEL + k0 + scol],      &Bs[tid * 8]);
        stage16(&W[(size_t)(n0 + 64 + srow) * D_MODEL + k0 + scol], &Bs[2048 + tid * 8]);
        __syncthreads();
        f16x8 af[4], bf[2];
#pragma unroll
        for (int mt = 0; mt < 4; ++mt) af[mt] = *(const f16x8*)&As[(mt * 16 + l15) * 32 + lhi * 8];
#pragma unroll
        for (int nt = 0; nt < 2; ++nt) bf[nt] = *(const f16x8*)&Bs[(w * 32 + nt * 16 + l15) * 32 + lhi * 8];
#pragma unroll
        for (int mt = 0; mt < 4; ++mt)
#pragma unroll
            for (int nt = 0; nt < 2; ++nt)
                acc[mt][nt] = __builtin_amdgcn_mfma_f32_16x16x32_f16(af[mt], bf[nt], acc[mt][nt], 0, 0, 0);
    }

#pragma unroll
    for (int mt = 0; mt < 4; ++mt)
#pragma unroll
        for (int nt = 0; nt < 2; ++nt) {
            const int n = n0 + w * 32 + nt * 16 + l15;
            const float bn = bias[n];
#pragma unroll
            for (int r = 0; r < 4; ++r) {
                const int m = m0 + mt * 16 + lhi * 4 + r;
                Y[(size_t)m * D_MODEL + n] = acc[mt][nt][r] + bn;
            }
        }
}

// ---------------------------------------------------------------------------
// ZERO-LDS flash attention. Grid = 512 blocks (16 qt x 32 bh), XCD-swizzled
// so each XCD's 64 blocks cover 4 bh -> K/V working set 2MB, L2-resident.
// 4 waves x 32 q-rows (two 16-col MFMA sets sharing K/V loads). All operands
// loaded as 16B-contiguous global fragments; no barriers, no LDS.
// K(t+1) register-prefetched; V(t) issued at tile top, consumed after softmax.
// ---------------------------------------------------------------------------
__global__ __launch_bounds__(256) void flash_mfma(const f16* __restrict__ qh, const f16* __restrict__ kh,
                                                  const f16* __restrict__ vt, f16* __restrict__ ao) {
    const int tid = threadIdx.x;
    const int lane = tid & 63;
    const int w = tid >> 6;
    const int c = lane & 15, g = lane >> 4;
    const int bid = blockIdx.x;
    const int swz = (bid & 7) * 64 + (bid >> 3);   // bijective (512 % 8 == 0)
    const int bh = swz >> 4, qt = swz & 15;
    const int b = bh >> 4, h = bh & 15;
    const int qbase = qt * 128 + w * 32;

    const f16* kbase = kh + (size_t)bh * S_LEN * DK;
    const f16* vbase = vt + (size_t)bh * DK * S_LEN;

    // Q as B-operand, two q-sets (pre-scaled by 0.125*log2e in the projection)
    f16x8 bQ[2][2];
#pragma unroll
    for (int s = 0; s < 2; ++s) {
        const f16* qp = qh + ((size_t)bh * S_LEN + qbase + s * 16 + c) * DK;
        bQ[s][0] = *(const f16x8*)&qp[g * 8];
        bQ[s][1] = *(const f16x8*)&qp[32 + g * 8];
    }

    f32x4 oa[2][4] = {};                 // O[set][q=g*4+r][d=nt2*16+c]
    float m_run[2] = {-INFINITY, -INFINITY};
    float l_run[2] = {0.f, 0.f};

    // prologue: K(0) fragments
    f16x8 kf[8];
#pragma unroll
    for (int nt = 0; nt < 4; ++nt) {
        const f16* kp = &kbase[(size_t)(nt * 16 + c) * DK];
        kf[nt * 2]     = *(const f16x8*)&kp[g * 8];
        kf[nt * 2 + 1] = *(const f16x8*)&kp[32 + g * 8];
    }

    for (int kt = 0; kt < S_LEN / 64; ++kt) {
        // issue V(kt) loads now; consumed after QK+softmax (latency hidden)
        f16x8 vf[8];
#pragma unroll
        for (int nt2 = 0; nt2 < 4; ++nt2) {
            const f16* vp = &vbase[(size_t)(nt2 * 16 + c) * S_LEN + kt * 64];
            vf[nt2 * 2]     = *(const f16x8*)&vp[g * 8];
            vf[nt2 * 2 + 1] = *(const f16x8*)&vp[32 + g * 8];
        }

        // swapped QK^T for both q-sets: sc[s][nt][r] = S'[key=nt*16+g*4+r][q=c]
        f32x4 sc[2][4] = {};
        __builtin_amdgcn_s_setprio(1);
#pragma unroll
        for (int nt = 0; nt < 4; ++nt) {
#pragma unroll
            for (int s = 0; s < 2; ++s) {
                sc[s][nt] = __builtin_amdgcn_mfma_f32_16x16x32_f16(kf[nt * 2],     bQ[s][0], sc[s][nt], 0, 0, 0);
                sc[s][nt] = __builtin_amdgcn_mfma_f32_16x16x32_f16(kf[nt * 2 + 1], bQ[s][1], sc[s][nt], 0, 0, 0);
            }
        }
        __builtin_amdgcn_s_setprio(0);

        // K(kt) consumed -> prefetch K(kt+1)
        if (kt + 1 < S_LEN / 64) {
#pragma unroll
            for (int nt = 0; nt < 4; ++nt) {
                const f16* kp = &kbase[(size_t)((kt + 1) * 64 + nt * 16 + c) * DK];
                kf[nt * 2]     = *(const f16x8*)&kp[g * 8];
                kf[nt * 2 + 1] = *(const f16x8*)&kp[32 + g * 8];
            }
        }

        // softmax + PV per set
#pragma unroll
        for (int s = 0; s < 2; ++s) {
            float tmax = sc[s][0][0];
#pragma unroll
            for (int nt = 0; nt < 4; ++nt)
#pragma unroll
                for (int r = 0; r < 4; ++r) tmax = fmaxf(tmax, sc[s][nt][r]);
            tmax = fmaxf(tmax, __shfl_xor(tmax, 16));
            tmax = fmaxf(tmax, __shfl_xor(tmax, 32));

            // defer-max (T13): rescale only when some row's max grew by >8
            if (!__all(tmax <= m_run[s] + 8.f)) {
                const float mnew = fmaxf(m_run[s], tmax);
                const float fac = exp2_fast(m_run[s] - mnew);
                m_run[s] = mnew;
                l_run[s] *= fac;
#pragma unroll
                for (int r = 0; r < 4; ++r) {
                    const float fr = __shfl(fac, (lane & 48) + ((lane >> 4) & 3) * 4 + r);
                    oa[s][0][r] *= fr; oa[s][1][r] *= fr; oa[s][2][r] *= fr; oa[s][3][r] *= fr;
                }
            }

            float e[4][4];
            float tsum = 0.f;
#pragma unroll
            for (int nt = 0; nt < 4; ++nt)
#pragma unroll
                for (int r = 0; r < 4; ++r) {
                    e[nt][r] = exp2_fast(sc[s][nt][r] - m_run[s]);
                    tsum += e[nt][r];
                }
            tsum += __shfl_xor(tsum, 16);
            tsum += __shfl_xor(tsum, 32);
            l_run[s] += tsum;

            const f16x8 aP0 = {(f16)e[0][0], (f16)e[0][1], (f16)e[0][2], (f16)e[0][3],
                               (f16)e[1][0], (f16)e[1][1], (f16)e[1][2], (f16)e[1][3]};
            const f16x8 aP1 = {(f16)e[2][0], (f16)e[2][1], (f16)e[2][2], (f16)e[2][3],
                               (f16)e[3][0], (f16)e[3][1], (f16)e[3][2], (f16)e[3][3]};

            __builtin_amdgcn_s_setprio(1);
#pragma unroll
            for (int nt2 = 0; nt2 < 4; ++nt2) {
                oa[s][nt2] = __builtin_amdgcn_mfma_f32_16x16x32_f16(aP0, vf[nt2 * 2],     oa[s][nt2], 0, 0, 0);
                oa[s][nt2] = __builtin_amdgcn_mfma_f32_16x16x32_f16(aP1, vf[nt2 * 2 + 1], oa[s][nt2], 0, 0, 0);
            }
            __builtin_amdgcn_s_setprio(0);
        }
    }

    // epilogue
#pragma unroll
    for (int s = 0; s < 2; ++s) {
        const float invc = 1.f / l_run[s];
#pragma unroll
        for (int r = 0; r < 4; ++r) {
            const float ir = __shfl(invc, (lane & 48) + ((lane >> 4) & 3) * 4 + r);
            const int srow = qbase + s * 16 + g * 4 + r;
#pragma unroll
            for (int nt2 = 0; nt2 < 4; ++nt2) {
                ao[((size_t)b * S_LEN + srow) * D_MODEL + h * DK + nt2 * 16 + c] = (f16)(oa[s][nt2][r] * ir);
            }
        }
    }
}

// ---------------------------------------------------------------------------
extern "C" void kernel_launch(void* const* d_in, const int* in_sizes, int n_in,
                              void* d_out, int out_size, void* d_ws, size_t ws_size,
                              hipStream_t stream) {
    const float* Q  = (const float*)d_in[0];
    const float* K  = (const float*)d_in[1];
    const float* V  = (const float*)d_in[2];
    const float* Wq = (const float*)d_in[3];
    const float* bq = (const float*)d_in[4];
    const float* Wk = (const float*)d_in[5];
    const float* bk = (const float*)d_in[6];
    const float* Wv = (const float*)d_in[7];
    const float* bv = (const float*)d_in[8];
    const float* Wo = (const float*)d_in[9];
    const float* bo = (const float*)d_in[10];
    float* out = (float*)d_out;

    const size_t NELEM = (size_t)M_ROWS * D_MODEL;   // 4M
    const size_t WELEM = (size_t)D_MODEL * D_MODEL;  // 1M
    f16* Qf  = (f16*)d_ws;
    f16* Kf  = Qf + NELEM;
    f16* Vf  = Kf + NELEM;
    f16* Wqf = Vf + NELEM;
    f16* Wkf = Wqf + WELEM;
    f16* Wvf = Wkf + WELEM;
    f16* Wof = Wvf + WELEM;
    f16* qh  = Wof + WELEM;   // [bh][s][dk], pre-scaled by 0.125*log2e
    f16* kh  = qh + NELEM;    // [bh][s][dk]
    f16* vtw = kh + NELEM;    // [bh][dk][s'] (perm6 key order)
    f16* aow = vtw + NELEM;   // [b][s][d_model] f16

    cvt_f32_to_f16<<<dim3(2048, 3), 256, 0, stream>>>(Q, K, V, nullptr, Qf, Kf, Vf, nullptr,
                                                      (int)(NELEM / 8));
    cvt_f32_to_f16<<<dim3(512, 4), 256, 0, stream>>>(Wq, Wk, Wv, Wo, Wqf, Wkf, Wvf, Wof,
                                                     (int)(WELEM / 8));
    qkv_gemm<<<dim3(D_MODEL / 128, M_ROWS / 128, 3), 256, 0, stream>>>(
        Qf, Kf, Vf, Wqf, Wkf, Wvf, bq, bk, bv, qh, kh, vtw);
    flash_mfma<<<512, 256, 0, stream>>>(qh, kh, vtw, aow);
    out_gemm<<<dim3(D_MODEL / 128, M_ROWS / 64), 256, 0, stream>>>(aow, Wof, bo, out);
}